// Round 3
// baseline (139.120 us; speedup 1.0000x reference)
//
#include <hip/hip_runtime.h>
#include <math.h>

// Problem constants
#define RDIM 512
#define MDIM 4
#define LDIM 256
#define BDIM 8192
#define NROWS (BDIM * (RDIM / MDIM))   // 1048576 rows of m=4
#define SIGMA_EPS 1e-4f
#define LOG2E 1.4426950408889634f

#define BLOCK 256
#define RPT 8                          // rows per thread
#define NGROUP (RPT / 2)               // 4 packed v2f row-groups
#define CHUNK 8                        // centers per register-chunk
#define NCHUNK (LDIM / CHUNK)          // 32
#define WSTRIDE 48                     // dwords per chunk in ws: 32 c + 8 nb + 8 pad (16B aligned)
#define GRID (NROWS / (BLOCK * RPT))   // 512

typedef float v2f __attribute__((ext_vector_type(2)));

static __device__ __forceinline__ v2f splat(float x) { v2f r; r.x = x; r.y = x; return r; }
static __device__ __forceinline__ v2f pk_fma(v2f a, v2f b, v2f c) { return __builtin_elementwise_fma(a, b, c); }
static __device__ __forceinline__ v2f pk_max(v2f a, v2f b) { return __builtin_elementwise_max(a, b); }
static __device__ __forceinline__ v2f exp2_pk(v2f v) {
    v2f r; r.x = __builtin_amdgcn_exp2f(v.x); r.y = __builtin_amdgcn_exp2f(v.y); return r;
}

// Prep: repack codebook + per-center bias into ws, chunk-major, s_load-friendly.
// Layout per chunk g (48 dwords): [0..31] center j component m at 4*j+m,
// [32..39] nb_j = -sig*log2e*||c_j||^2, [40..47] pad.
__global__ void prep_kernel(const float* __restrict__ c,
                            const float* __restrict__ sigma,
                            float* __restrict__ w)
{
    const int l = threadIdx.x;                 // 0..255, one center per thread
    const float sig  = fmaxf(sigma[0], 0.0f) + SIGMA_EPS;
    const float sigL = sig * LOG2E;
    const float c0 = c[0 * LDIM + l];
    const float c1 = c[1 * LDIM + l];
    const float c2 = c[2 * LDIM + l];
    const float c3 = c[3 * LDIM + l];
    const int g = l >> 3, j = l & 7;
    float* wc = w + g * WSTRIDE;
    wc[4 * j + 0] = c0;
    wc[4 * j + 1] = c1;
    wc[4 * j + 2] = c2;
    wc[4 * j + 3] = c3;
    wc[32 + j] = -sigL * fmaf(c0, c0, fmaf(c1, c1, fmaf(c2, c2, c3 * c3)));
}

// Main: codebook comes in through scalar loads (uniform indices -> SGPRs),
// no LDS, no barriers. Two rows packed per v2f (v_pk_*_f32), 4 groups/thread.
// Score (exp2 domain): s = (2 sig log2e)*(z.c) - sig log2e*||c||^2; z prescaled.
// Flash-style chunked softmax: exact chunk max, one rescale per chunk.
__global__ __launch_bounds__(BLOCK, 2) void soft_quantize_kernel(
    const float4* __restrict__ x4,    // NROWS float4
    const float*  __restrict__ w,     // prep output (uniform reads)
    const float*  __restrict__ sigma, // 1 element
    float4*       __restrict__ out4)  // NROWS float4
{
    const int tid  = threadIdx.x;
    const int base = blockIdx.x * (BLOCK * RPT) + tid;

    const float sig   = fmaxf(sigma[0], 0.0f) + SIGMA_EPS;
    const float sig2L = 2.0f * sig * LOG2E;

    float4 z[RPT];
    #pragma unroll
    for (int k = 0; k < RPT; ++k) z[k] = x4[base + k * BLOCK];

    v2f zx[NGROUP], zy[NGROUP], zz[NGROUP], zw[NGROUP];
    #pragma unroll
    for (int g = 0; g < NGROUP; ++g) {
        zx[g].x = z[2 * g].x * sig2L; zx[g].y = z[2 * g + 1].x * sig2L;
        zy[g].x = z[2 * g].y * sig2L; zy[g].y = z[2 * g + 1].y * sig2L;
        zz[g].x = z[2 * g].z * sig2L; zz[g].y = z[2 * g + 1].z * sig2L;
        zw[g].x = z[2 * g].w * sig2L; zw[g].y = z[2 * g + 1].w * sig2L;
    }

    v2f mx[NGROUP], den[NGROUP], ax[NGROUP], ay[NGROUP], az[NGROUP], aw[NGROUP];
    #pragma unroll
    for (int g = 0; g < NGROUP; ++g) {
        mx[g] = splat(-1e30f); den[g] = splat(0.f);
        ax[g] = splat(0.f); ay[g] = splat(0.f); az[g] = splat(0.f); aw[g] = splat(0.f);
    }

    for (int ch = 0; ch < NCHUNK; ++ch) {
        const float* wc = w + ch * WSTRIDE;
        float c0[CHUNK], c1[CHUNK], c2[CHUNK], c3[CHUNK];
        v2f   bnb[CHUNK];
        #pragma unroll
        for (int j = 0; j < CHUNK; ++j) {
            c0[j] = wc[4 * j + 0];      // uniform -> s_load -> SGPR
            c1[j] = wc[4 * j + 1];
            c2[j] = wc[4 * j + 2];
            c3[j] = wc[4 * j + 3];
            bnb[j] = splat(wc[32 + j]); // VGPR pair, shared by all 4 groups
        }

        #pragma unroll
        for (int g = 0; g < NGROUP; ++g) {
            v2f s[CHUNK];
            #pragma unroll
            for (int j = 0; j < CHUNK; ++j) {
                v2f t = pk_fma(zx[g], splat(c0[j]), bnb[j]);
                t     = pk_fma(zy[g], splat(c1[j]), t);
                t     = pk_fma(zz[g], splat(c2[j]), t);
                s[j]  = pk_fma(zw[g], splat(c3[j]), t);
            }
            v2f mc = pk_max(pk_max(pk_max(s[0], s[1]), pk_max(s[2], s[3])),
                            pk_max(pk_max(s[4], s[5]), pk_max(s[6], s[7])));
            v2f mn = pk_max(mx[g], mc);
            v2f al = exp2_pk(mx[g] - mn);
            den[g] = den[g] * al;
            ax[g] = ax[g] * al; ay[g] = ay[g] * al;
            az[g] = az[g] * al; aw[g] = aw[g] * al;
            #pragma unroll
            for (int j = 0; j < CHUNK; ++j) {
                v2f e = exp2_pk(s[j] - mn);
                den[g] = den[g] + e;
                ax[g] = pk_fma(e, splat(c0[j]), ax[g]);
                ay[g] = pk_fma(e, splat(c1[j]), ay[g]);
                az[g] = pk_fma(e, splat(c2[j]), az[g]);
                aw[g] = pk_fma(e, splat(c3[j]), aw[g]);
            }
            mx[g] = mn;
        }
    }

    #pragma unroll
    for (int g = 0; g < NGROUP; ++g) {
        const float i0 = 1.0f / den[g].x;
        const float i1 = 1.0f / den[g].y;
        out4[base + (2 * g) * BLOCK] =
            make_float4(ax[g].x * i0, ay[g].x * i0, az[g].x * i0, aw[g].x * i0);
        out4[base + (2 * g + 1) * BLOCK] =
            make_float4(ax[g].y * i1, ay[g].y * i1, az[g].y * i1, aw[g].y * i1);
    }
}

extern "C" void kernel_launch(void* const* d_in, const int* in_sizes, int n_in,
                              void* d_out, int out_size, void* d_ws, size_t ws_size,
                              hipStream_t stream) {
    const float4* x4    = (const float4*)d_in[0];  // (B, R) fp32 = NROWS float4
    const float*  c     = (const float*)d_in[1];   // (M, L) fp32
    const float*  sigma = (const float*)d_in[2];   // (1,)  fp32
    float4*       out4  = (float4*)d_out;          // (B, R) fp32
    float*        w     = (float*)d_ws;            // NCHUNK*WSTRIDE floats = 6 KiB

    prep_kernel<<<1, LDIM, 0, stream>>>(c, sigma, w);
    soft_quantize_kernel<<<GRID, BLOCK, 0, stream>>>(x4, w, sigma, out4);
}

// Round 5
// 127.148 us; speedup vs baseline: 1.0942x; 1.0942x over previous
//
#include <hip/hip_runtime.h>
#include <math.h>

// Problem constants
#define RDIM 512
#define MDIM 4
#define LDIM 256
#define BDIM 8192
#define NROWS (BDIM * (RDIM / MDIM))   // 1048576 rows of m=4
#define SIGMA_EPS 1e-4f
#define LOG2E 1.4426950408889634f

typedef _Float16 half2_t __attribute__((ext_vector_type(2)));
typedef _Float16 half4_t __attribute__((ext_vector_type(4)));
typedef _Float16 half8_t __attribute__((ext_vector_type(8)));
typedef __fp16   fp16x2_t __attribute__((ext_vector_type(2)));
typedef float    float4_t __attribute__((ext_vector_type(4)));

#define NRT (NROWS / 16)          // 65536 row-tiles of 16 z-rows
#define MAIN_BLOCKS 2048
#define WPB 4                      // waves per block
#define NT (NRT / (MAIN_BLOCKS * WPB))   // 8 row-tiles per wave
#define QSTRIDE 264                // f16 per zrow in LDS (256 + 8 pad) = 528 B, 16B-aligned

// ---------------- prep: build MFMA A-operand fragments in ws ----------------
// GEMM1 (scores S^T = Cmat @ Zmat): A1[m=center][k], 16 tiles of 16 centers.
//   k slots: 0..3 u_hi, 4..7 u_hi, 8..11 u_lo, 12 b_hi, 13 b_lo, rest 0
//   where u = 2*sig*log2e * c (hi/lo f16 split), b = -sig*log2e*||c||^2 (split).
//   Pairs with B1 z-slots [z_hi, z_lo, z_hi, 1, 1] -> fp32-accurate score.
// GEMM2 (out^T = C2 @ Q^T): A2[m][k=center], m=0..3 -> c[m][k], m=4 -> 1 (den row).
// Fragment layout (16x16x32): lane holds m=lane&15, k=(lane>>4)*8 + j, j=0..7.
__global__ void prep_kernel(const float* __restrict__ c, const float* __restrict__ sigma,
                            _Float16* __restrict__ a1w, _Float16* __restrict__ a2w) {
  const int gid  = blockIdx.x * 256 + threadIdx.x;
  const int lane = gid & 63;
  const int q4   = lane >> 4;
  const int m    = lane & 15;
  const float sig   = fmaxf(sigma[0], 0.0f) + SIGMA_EPS;
  const float sigL  = sig * LOG2E;
  const float sig2L = 2.0f * sigL;
  if (gid < 1024) {
    const int t = gid >> 6;        // A1 tile
    const int l = t * 16 + m;      // center
    float cv[4];
    cv[0] = c[l]; cv[1] = c[256 + l]; cv[2] = c[512 + l]; cv[3] = c[768 + l];
    _Float16 uh[4], ul[4];
    #pragma unroll
    for (int i = 0; i < 4; ++i) {
      float u = sig2L * cv[i];
      uh[i] = (_Float16)u;
      ul[i] = (_Float16)(u - (float)uh[i]);
    }
    float bias = -sigL * fmaf(cv[0], cv[0], fmaf(cv[1], cv[1], fmaf(cv[2], cv[2], cv[3] * cv[3])));
    _Float16 bh = (_Float16)bias;
    _Float16 bl = (_Float16)(bias - (float)bh);
    #pragma unroll
    for (int j = 0; j < 8; ++j) {
      int k = q4 * 8 + j;
      _Float16 v = (_Float16)0.0f;
      if      (k < 4)   v = uh[k];
      else if (k < 8)   v = uh[k - 4];
      else if (k < 12)  v = ul[k - 8];
      else if (k == 12) v = bh;
      else if (k == 13) v = bl;
      a1w[(t * 64 + lane) * 8 + j] = v;
    }
  } else if (gid < 1536) {
    const int p = (gid - 1024) >> 6;   // A2 K-tile
    #pragma unroll
    for (int j = 0; j < 8; ++j) {
      int k = 32 * p + q4 * 8 + j;     // center
      _Float16 v = (_Float16)0.0f;
      if (m < 4)       v = (_Float16)c[m * 256 + k];
      else if (m == 4) v = (_Float16)1.0f;
      a2w[(p * 64 + lane) * 8 + j] = v;
    }
  }
}

// ---------------- main ----------------
// Per wave, per 16-row tile:
//  GEMM1: 16 MFMA -> S^T tiles, D layout: zrow = lane&15 (col), center = 16t + 4*(lane>>4) + reg.
//  VALU: max over 256 (64 in-lane + shfl_xor 16/32), exp2(s - m), cvt to f16.
//  LDS: write q (D layout) / read back as B-operand rows-of-8 (the P->A transform).
//  GEMM2: 8 MFMA vs C2=[c;1]: D2 quad0 lanes hold out float4 (rows 0..3), den at row 4
//  (quad1 reg0) -> one shfl, rcp, coalesced float4 store by lanes 0..15.
__global__ __launch_bounds__(256, 2) void sq_mfma_kernel(
    const float4* __restrict__ x4,
    const _Float16* __restrict__ a1w,
    const _Float16* __restrict__ a2w,
    float4* __restrict__ out4) {
  const int tid  = threadIdx.x;
  const int lane = tid & 63;
  const int wave = tid >> 6;
  const int q4   = lane >> 4;
  const int zr   = lane & 15;

  __shared__ __align__(16) _Float16 qlds_all[WPB][16 * QSTRIDE];
  _Float16* qlds = &qlds_all[wave][0];

  // preload loop-invariant A fragments
  half8_t a1[16], a2[8];
  const half8_t* a1p = (const half8_t*)a1w;
  const half8_t* a2p = (const half8_t*)a2w;
  #pragma unroll
  for (int t = 0; t < 16; ++t) a1[t] = a1p[t * 64 + lane];
  #pragma unroll
  for (int p = 0; p < 8; ++p) a2[p] = a2p[p * 64 + lane];

  const int gw = blockIdx.x * WPB + wave;
  const float4_t zero4 = {0.f, 0.f, 0.f, 0.f};

  for (int it = 0; it < NT; ++it) {
    const int rt = gw * NT + it;
    const int rowbase = rt * 16;

    const float4 z = x4[rowbase + zr];
    // hi/lo split of z
    _Float16 zh0 = (_Float16)z.x, zh1 = (_Float16)z.y, zh2 = (_Float16)z.z, zh3 = (_Float16)z.w;
    _Float16 zl0 = (_Float16)(z.x - (float)zh0);
    _Float16 zl1 = (_Float16)(z.y - (float)zh1);
    _Float16 zl2 = (_Float16)(z.z - (float)zh2);
    _Float16 zl3 = (_Float16)(z.w - (float)zh3);

    const _Float16 h0 = (_Float16)0.0f, h1 = (_Float16)1.0f;
    half8_t b1;
    b1[0] = (q4 < 2) ? zh0 : h0;
    b1[1] = (q4 < 2) ? zh1 : h0;
    b1[2] = (q4 < 2) ? zh2 : h0;
    b1[3] = (q4 < 2) ? zh3 : h0;
    b1[4] = (q4 == 0) ? zl0 : ((q4 == 1) ? h1 : h0);
    b1[5] = (q4 == 0) ? zl1 : ((q4 == 1) ? h1 : h0);
    b1[6] = (q4 == 0) ? zl2 : h0;
    b1[7] = (q4 == 0) ? zl3 : h0;

    // GEMM1: scores
    float4_t s[16];
    #pragma unroll
    for (int t = 0; t < 16; ++t)
      s[t] = __builtin_amdgcn_mfma_f32_16x16x32_f16(a1[t], b1, zero4, 0, 0, 0);

    // max over all 256 centers for this zrow
    float mx = -3.0e38f;
    #pragma unroll
    for (int t = 0; t < 16; ++t) {
      mx = fmaxf(mx, fmaxf(fmaxf(s[t][0], s[t][1]), fmaxf(s[t][2], s[t][3])));
    }
    mx = fmaxf(mx, __shfl_xor(mx, 16));
    mx = fmaxf(mx, __shfl_xor(mx, 32));

    // exp2, cvt to f16, stage to LDS (write in D layout)
    #pragma unroll
    for (int t = 0; t < 16; ++t) {
      float e0 = __builtin_amdgcn_exp2f(s[t][0] - mx);
      float e1 = __builtin_amdgcn_exp2f(s[t][1] - mx);
      float e2 = __builtin_amdgcn_exp2f(s[t][2] - mx);
      float e3 = __builtin_amdgcn_exp2f(s[t][3] - mx);
      fp16x2_t lo = __builtin_amdgcn_cvt_pkrtz(e0, e1);
      fp16x2_t hi = __builtin_amdgcn_cvt_pkrtz(e2, e3);
      half4_t w;
      w[0] = (_Float16)lo[0]; w[1] = (_Float16)lo[1];
      w[2] = (_Float16)hi[0]; w[3] = (_Float16)hi[1];
      *(half4_t*)&qlds[zr * QSTRIDE + 16 * t + 4 * q4] = w;
    }

    // same-wave DS ops are in-order; barrier only against compiler reordering
    asm volatile("" ::: "memory");

    // GEMM2: read q back as B-operand (k = 32p + 8*q4 + j, n = zr), accumulate
    float4_t d2 = zero4;
    #pragma unroll
    for (int p = 0; p < 8; ++p) {
      half8_t b2 = *(const half8_t*)&qlds[zr * QSTRIDE + 32 * p + 8 * q4];
      d2 = __builtin_amdgcn_mfma_f32_16x16x32_f16(a2[p], b2, d2, 0, 0, 0);
    }

    // den lives at D2 row 4 = quad1 reg0; out comps at rows 0..3 = quad0 regs
    float den = __shfl(d2[0], zr + 16);
    if (lane < 16) {
      float r = __builtin_amdgcn_rcpf(den);
      float4 o = make_float4(d2[0] * r, d2[1] * r, d2[2] * r, d2[3] * r);
      out4[rowbase + zr] = o;
    }
  }
}

extern "C" void kernel_launch(void* const* d_in, const int* in_sizes, int n_in,
                              void* d_out, int out_size, void* d_ws, size_t ws_size,
                              hipStream_t stream) {
  const float4* x4    = (const float4*)d_in[0];  // (B, R) fp32 = NROWS float4
  const float*  c     = (const float*)d_in[1];   // (M, L) fp32
  const float*  sigma = (const float*)d_in[2];   // (1,)  fp32
  float4*       out4  = (float4*)d_out;          // (B, R) fp32

  _Float16* a1w = (_Float16*)d_ws;               // 16*64*8 f16 = 16 KiB
  _Float16* a2w = a1w + 16 * 64 * 8;             //  8*64*8 f16 =  8 KiB

  prep_kernel<<<6, 256, 0, stream>>>(c, sigma, a1w, a2w);
  sq_mfma_kernel<<<MAIN_BLOCKS, 256, 0, stream>>>(x4, a1w, a2w, out4);
}

// Round 6
// 120.106 us; speedup vs baseline: 1.1583x; 1.0586x over previous
//
#include <hip/hip_runtime.h>
#include <math.h>

// Problem constants
#define RDIM 512
#define MDIM 4
#define LDIM 256
#define BDIM 8192
#define NROWS (BDIM * (RDIM / MDIM))   // 1048576 rows of m=4
#define SIGMA_EPS 1e-4f
#define LOG2E 1.4426950408889634f

typedef _Float16 half4_t __attribute__((ext_vector_type(4)));
typedef _Float16 half8_t __attribute__((ext_vector_type(8)));
typedef __fp16   fp16x2_t __attribute__((ext_vector_type(2)));
typedef float    float4_t __attribute__((ext_vector_type(4)));

#define NRT (NROWS / 16)          // 65536 row-tiles of 16 z-rows
#define MAIN_BLOCKS 2048
#define WPB 4                      // waves per block
#define NT (NRT / (MAIN_BLOCKS * WPB))   // 8 row-tiles per wave

// ---------------- prep: build MFMA A-operand fragments in ws ----------------
// GEMM1 (scores S^T = Cmat @ Zmat): A1[m=center][k], 16 tiles of 16 centers.
//   k slots: 0..3 u_hi, 4..7 u_hi, 8..11 u_lo, 12 b_hi, 13 b_lo, rest 0
//   (u = 2*sig*log2e * c hi/lo split, b = -sig*log2e*||c||^2 split) paired with
//   B1 z-slots [z_hi | z_lo | z_hi | 1,1] -> fp32-accurate score.
// GEMM2 (out^T = C2 @ Q): A2[m][k] for K-tile p uses the PERMUTED center order
//   center(p, k=8Q+j) = 32p + 16*(j>>2) + 4Q + (j&3)
// chosen so the B-operand q-fragment is exactly lane-local GEMM1 D registers:
// B2 lane(zr,q4) k=8*q4+j  <->  D1 tile 2p+(j>>2), reg j&3, col zr. No LDS.
// A/B fragment layout (16x16x32): lane holds 8 k's at k=(lane>>4)*8+j; m/n=lane&15.
__global__ void prep_kernel(const float* __restrict__ c, const float* __restrict__ sigma,
                            _Float16* __restrict__ a1w, _Float16* __restrict__ a2w) {
  const int gid  = blockIdx.x * 256 + threadIdx.x;
  const int lane = gid & 63;
  const int q4   = lane >> 4;
  const int m    = lane & 15;
  const float sig   = fmaxf(sigma[0], 0.0f) + SIGMA_EPS;
  const float sigL  = sig * LOG2E;
  const float sig2L = 2.0f * sigL;
  if (gid < 1024) {
    const int t = gid >> 6;        // A1 tile
    const int l = t * 16 + m;      // center
    float cv[4];
    cv[0] = c[l]; cv[1] = c[256 + l]; cv[2] = c[512 + l]; cv[3] = c[768 + l];
    _Float16 uh[4], ul[4];
    #pragma unroll
    for (int i = 0; i < 4; ++i) {
      float u = sig2L * cv[i];
      uh[i] = (_Float16)u;
      ul[i] = (_Float16)(u - (float)uh[i]);
    }
    float bias = -sigL * fmaf(cv[0], cv[0], fmaf(cv[1], cv[1], fmaf(cv[2], cv[2], cv[3] * cv[3])));
    _Float16 bh = (_Float16)bias;
    _Float16 bl = (_Float16)(bias - (float)bh);
    #pragma unroll
    for (int j = 0; j < 8; ++j) {
      int k = q4 * 8 + j;
      _Float16 v = (_Float16)0.0f;
      if      (k < 4)   v = uh[k];
      else if (k < 8)   v = uh[k - 4];
      else if (k < 12)  v = ul[k - 8];
      else if (k == 12) v = bh;
      else if (k == 13) v = bl;
      a1w[(t * 64 + lane) * 8 + j] = v;
    }
  } else if (gid < 1536) {
    const int p = (gid - 1024) >> 6;   // A2 K-tile
    #pragma unroll
    for (int j = 0; j < 8; ++j) {
      int center = 32 * p + 16 * (j >> 2) + 4 * q4 + (j & 3);   // permuted order
      _Float16 v = (_Float16)0.0f;
      if (m < 4)       v = (_Float16)c[m * 256 + center];
      else if (m == 4) v = (_Float16)1.0f;
      a2w[(p * 64 + lane) * 8 + j] = v;
    }
  }
}

// ---------------- main ----------------
// Per wave, per 16-row tile:
//  GEMM1: 16 MFMA -> S^T, D layout: zrow = lane&15, center = 16t + 4*(lane>>4) + reg.
//  VALU: max over 256 (in-lane + shfl_xor 16/32), exp2(s - mx), cvt_pkrtz to f16.
//  GEMM2: 8 MFMA vs permuted C2=[c;1]; B-fragment = lane-local e values (no LDS!).
//  D2 quad0 lanes hold out float4 (m rows 0..3), den at m=4 (quad1 reg0) -> one shfl.
__global__ __launch_bounds__(256, 2) void sq_mfma_kernel(
    const float4* __restrict__ x4,
    const _Float16* __restrict__ a1w,
    const _Float16* __restrict__ a2w,
    float4* __restrict__ out4) {
  const int tid  = threadIdx.x;
  const int lane = tid & 63;
  const int wave = tid >> 6;
  const int q4   = lane >> 4;
  const int zr   = lane & 15;

  // preload loop-invariant A fragments (stay in VGPR/AGPR)
  half8_t a1[16], a2[8];
  const half8_t* a1p = (const half8_t*)a1w;
  const half8_t* a2p = (const half8_t*)a2w;
  #pragma unroll
  for (int t = 0; t < 16; ++t) a1[t] = a1p[t * 64 + lane];
  #pragma unroll
  for (int p = 0; p < 8; ++p) a2[p] = a2p[p * 64 + lane];

  const int gw = blockIdx.x * WPB + wave;
  const float4_t zero4 = {0.f, 0.f, 0.f, 0.f};

  for (int it = 0; it < NT; ++it) {
    const int rowbase = (gw * NT + it) * 16;

    const float4 z = x4[rowbase + zr];
    // hi/lo split of z
    _Float16 zh0 = (_Float16)z.x, zh1 = (_Float16)z.y, zh2 = (_Float16)z.z, zh3 = (_Float16)z.w;
    _Float16 zl0 = (_Float16)(z.x - (float)zh0);
    _Float16 zl1 = (_Float16)(z.y - (float)zh1);
    _Float16 zl2 = (_Float16)(z.z - (float)zh2);
    _Float16 zl3 = (_Float16)(z.w - (float)zh3);

    const _Float16 h0 = (_Float16)0.0f, h1 = (_Float16)1.0f;
    half8_t b1;
    b1[0] = (q4 < 2) ? zh0 : h0;
    b1[1] = (q4 < 2) ? zh1 : h0;
    b1[2] = (q4 < 2) ? zh2 : h0;
    b1[3] = (q4 < 2) ? zh3 : h0;
    b1[4] = (q4 == 0) ? zl0 : ((q4 == 1) ? h1 : h0);
    b1[5] = (q4 == 0) ? zl1 : ((q4 == 1) ? h1 : h0);
    b1[6] = (q4 == 0) ? zl2 : h0;
    b1[7] = (q4 == 0) ? zl3 : h0;

    // GEMM1: scores
    float4_t s[16];
    #pragma unroll
    for (int t = 0; t < 16; ++t)
      s[t] = __builtin_amdgcn_mfma_f32_16x16x32_f16(a1[t], b1, zero4, 0, 0, 0);

    // max over all 256 centers for this zrow
    float mx = -3.0e38f;
    #pragma unroll
    for (int t = 0; t < 16; ++t)
      mx = fmaxf(mx, fmaxf(fmaxf(s[t][0], s[t][1]), fmaxf(s[t][2], s[t][3])));
    mx = fmaxf(mx, __shfl_xor(mx, 16));
    mx = fmaxf(mx, __shfl_xor(mx, 32));

    // GEMM2: B-fragment is lane-local exp2 results (permuted-center A2)
    float4_t d2 = zero4;
    #pragma unroll
    for (int p = 0; p < 8; ++p) {
      fp16x2_t e01a = __builtin_amdgcn_cvt_pkrtz(
          __builtin_amdgcn_exp2f(s[2 * p][0] - mx), __builtin_amdgcn_exp2f(s[2 * p][1] - mx));
      fp16x2_t e23a = __builtin_amdgcn_cvt_pkrtz(
          __builtin_amdgcn_exp2f(s[2 * p][2] - mx), __builtin_amdgcn_exp2f(s[2 * p][3] - mx));
      fp16x2_t e01b = __builtin_amdgcn_cvt_pkrtz(
          __builtin_amdgcn_exp2f(s[2 * p + 1][0] - mx), __builtin_amdgcn_exp2f(s[2 * p + 1][1] - mx));
      fp16x2_t e23b = __builtin_amdgcn_cvt_pkrtz(
          __builtin_amdgcn_exp2f(s[2 * p + 1][2] - mx), __builtin_amdgcn_exp2f(s[2 * p + 1][3] - mx));
      half8_t b2;
      b2[0] = (_Float16)e01a[0]; b2[1] = (_Float16)e01a[1];
      b2[2] = (_Float16)e23a[0]; b2[3] = (_Float16)e23a[1];
      b2[4] = (_Float16)e01b[0]; b2[5] = (_Float16)e01b[1];
      b2[6] = (_Float16)e23b[0]; b2[7] = (_Float16)e23b[1];
      d2 = __builtin_amdgcn_mfma_f32_16x16x32_f16(a2[p], b2, d2, 0, 0, 0);
    }

    // den lives at D2 row 4 = quad1 reg0; out comps at rows 0..3 = quad0 regs
    float den = __shfl(d2[0], zr + 16);
    if (lane < 16) {
      float r = __builtin_amdgcn_rcpf(den);
      float4 o = make_float4(d2[0] * r, d2[1] * r, d2[2] * r, d2[3] * r);
      out4[rowbase + zr] = o;
    }
  }
}

extern "C" void kernel_launch(void* const* d_in, const int* in_sizes, int n_in,
                              void* d_out, int out_size, void* d_ws, size_t ws_size,
                              hipStream_t stream) {
  const float4* x4    = (const float4*)d_in[0];  // (B, R) fp32 = NROWS float4
  const float*  c     = (const float*)d_in[1];   // (M, L) fp32
  const float*  sigma = (const float*)d_in[2];   // (1,)  fp32
  float4*       out4  = (float4*)d_out;          // (B, R) fp32

  _Float16* a1w = (_Float16*)d_ws;               // 16*64*8 f16 = 16 KiB
  _Float16* a2w = a1w + 16 * 64 * 8;             //  8*64*8 f16 =  8 KiB

  prep_kernel<<<6, 256, 0, stream>>>(c, sigma, a1w, a2w);
  sq_mfma_kernel<<<MAIN_BLOCKS, 256, 0, stream>>>(x4, a1w, a2w, out4);
}

// Round 8
// 114.697 us; speedup vs baseline: 1.2129x; 1.0472x over previous
//
#include <hip/hip_runtime.h>
#include <math.h>

// Problem constants
#define RDIM 512
#define MDIM 4
#define LDIM 256
#define BDIM 8192
#define NROWS (BDIM * (RDIM / MDIM))   // 1048576 rows of m=4
#define SIGMA_EPS 1e-4f
#define LOG2E 1.4426950408889634f

typedef _Float16 half4_t __attribute__((ext_vector_type(4)));
typedef _Float16 half8_t __attribute__((ext_vector_type(8)));
typedef __fp16   fp16x2_t __attribute__((ext_vector_type(2)));
typedef float    float4_t __attribute__((ext_vector_type(4)));

#define NRT (NROWS / 16)          // 65536 row-tiles of 16 z-rows
#define MAIN_BLOCKS 2048
#define WPB 4                      // waves per block
#define NT (NRT / (MAIN_BLOCKS * WPB))   // 8 row-tiles per wave

// ---------------- prep: build MFMA A-operand fragments in ws ----------------
// GEMM1 (scores S^T = Cmat @ Zmat), 16x16x16 f16, A1[m=center][k], 16 tiles:
//   A k slots by quad: q=0 -> uh0..3, q=1 -> uh0..3, q=2 -> ul0..3,
//                      q=3 -> [bh, bl, 1, 1]            <-- 1,1 carry the -mx terms!
//   (u = 2*sig*log2e*c hi/lo split, b = -sig*log2e*||c||^2 split), paired with
//   B1 z-slots: q=0 -> zh, q=1 -> zl, q=2 -> zh,
//   q=3 -> [1,1, 0,0] (phase A) / [1,1, -mx_h,-mx_l] (phase B)
//   -> s = u.z + b (- mx), fp32-accurate.
// GEMM2 (out^T = C2 @ Q), 16x16x32: A2[m][k] K-tile p in PERMUTED center order
//   center(p, k=8Q+j) = 32p + 16*(j>>2) + 4Q + (j&3)
// so B2 q-fragments are lane-local GEMM1 D registers (no LDS).
// 16x16x16 A/B layout: lane holds 4 k's at k=(lane>>4)*4+j; m/n = lane&15.
// 16x16x32 A/B layout: lane holds 8 k's at k=(lane>>4)*8+j; C/D rows = 4*(lane>>4)+reg.
__global__ void prep_kernel(const float* __restrict__ c, const float* __restrict__ sigma,
                            _Float16* __restrict__ a1w, _Float16* __restrict__ a2w) {
  const int gid  = blockIdx.x * 256 + threadIdx.x;
  const int lane = gid & 63;
  const int q4   = lane >> 4;
  const int m    = lane & 15;
  const float sig   = fmaxf(sigma[0], 0.0f) + SIGMA_EPS;
  const float sigL  = sig * LOG2E;
  const float sig2L = 2.0f * sigL;
  if (gid < 1024) {
    const int t = gid >> 6;        // A1 tile
    const int l = t * 16 + m;      // center
    float cv[4];
    cv[0] = c[l]; cv[1] = c[256 + l]; cv[2] = c[512 + l]; cv[3] = c[768 + l];
    _Float16 uh[4], ul[4];
    #pragma unroll
    for (int i = 0; i < 4; ++i) {
      float u = sig2L * cv[i];
      uh[i] = (_Float16)u;
      ul[i] = (_Float16)(u - (float)uh[i]);
    }
    float bias = -sigL * fmaf(cv[0], cv[0], fmaf(cv[1], cv[1], fmaf(cv[2], cv[2], cv[3] * cv[3])));
    _Float16 bh = (_Float16)bias;
    _Float16 bl = (_Float16)(bias - (float)bh);
    #pragma unroll
    for (int j = 0; j < 4; ++j) {
      _Float16 v;
      if      (q4 <  2) v = uh[j];
      else if (q4 == 2) v = ul[j];
      else              v = (j == 0) ? bh : ((j == 1) ? bl : (_Float16)1.0f);  // k14/k15 = 1 -> pair -mx
      a1w[(t * 64 + lane) * 4 + j] = v;
    }
  } else if (gid < 1536) {
    const int p = (gid - 1024) >> 6;   // A2 K-tile
    #pragma unroll
    for (int j = 0; j < 8; ++j) {
      int center = 32 * p + 16 * (j >> 2) + 4 * q4 + (j & 3);   // permuted order
      _Float16 v = (_Float16)0.0f;
      if (m < 4)       v = (_Float16)c[m * 256 + center];
      else if (m == 4) v = (_Float16)1.0f;
      a2w[(p * 64 + lane) * 8 + j] = v;
    }
  }
}

union U2H4 { uint2 u; half4_t h; };
union H4X2 { fp16x2_t e[4]; half8_t h8; };

// ---------------- main ----------------
// Per wave, per 16-row tile:
//  Phase A: 16x MFMA(16x16x16) -> running max over 256 centers (s transient, 4 regs).
//  Phase B: recompute s with -mx folded in via B1 q=3 slots (s = score - mx directly),
//           exp2 + cvt_pkrtz -> lane-local B2 fragments -> 8x MFMA(16x16x32) GEMM2.
//  D2: quad0 lanes hold out float4 (m rows 0..3); den at m=4 (quad1 reg0) -> one shfl.
__global__ __launch_bounds__(256, 4) void sq_mfma_kernel(
    const float4* __restrict__ x4,
    const _Float16* __restrict__ a1w,
    const _Float16* __restrict__ a2w,
    float4* __restrict__ out4) {
  const int tid  = threadIdx.x;
  const int lane = tid & 63;
  const int wave = tid >> 6;
  const int q4   = lane >> 4;
  const int zr   = lane & 15;

  // preload loop-invariant A fragments (persistent: 32 + 32 VGPRs)
  half4_t a1[16];
  half8_t a2[8];
  const half4_t* a1p = (const half4_t*)a1w;
  const half8_t* a2p = (const half8_t*)a2w;
  #pragma unroll
  for (int t = 0; t < 16; ++t) a1[t] = a1p[t * 64 + lane];
  #pragma unroll
  for (int p = 0; p < 8; ++p) a2[p] = a2p[p * 64 + lane];

  const int gw = blockIdx.x * WPB + wave;
  const float4_t zero4 = {0.f, 0.f, 0.f, 0.f};
  const unsigned one_one = 0x3C003C00u;   // f16 {1.0, 1.0}

  for (int it = 0; it < NT; ++it) {
    const int rowbase = (gw * NT + it) * 16;

    const float4 z = x4[rowbase + zr];
    // hi/lo split of z (packed)
    fp16x2_t zh01 = __builtin_amdgcn_cvt_pkrtz(z.x, z.y);
    fp16x2_t zh23 = __builtin_amdgcn_cvt_pkrtz(z.z, z.w);
    fp16x2_t zl01 = __builtin_amdgcn_cvt_pkrtz(z.x - (float)zh01[0], z.y - (float)zh01[1]);
    fp16x2_t zl23 = __builtin_amdgcn_cvt_pkrtz(z.z - (float)zh23[0], z.w - (float)zh23[1]);
    const unsigned zh01u = __builtin_bit_cast(unsigned, zh01);
    const unsigned zh23u = __builtin_bit_cast(unsigned, zh23);
    const unsigned zl01u = __builtin_bit_cast(unsigned, zl01);
    const unsigned zl23u = __builtin_bit_cast(unsigned, zl23);

    // B1 by quad: q0 -> zh (pairs uh), q1 -> zl (pairs uh), q2 -> zh (pairs ul),
    // q3 -> [1,1 | 0,0] (phase A) / [1,1 | -mx_h,-mx_l] (phase B)
    const unsigned w0 = (q4 == 1) ? zl01u : ((q4 == 3) ? one_one : zh01u);
    const unsigned w1A = (q4 == 3) ? 0u : ((q4 == 1) ? zl23u : zh23u);
    U2H4 b1a; b1a.u = make_uint2(w0, w1A);

    // ---- Phase A: exact max over 256 centers ----
    float mx = -3.0e38f;
    #pragma unroll
    for (int t = 0; t < 16; ++t) {
      float4_t s = __builtin_amdgcn_mfma_f32_16x16x16f16(a1[t], b1a.h, zero4, 0, 0, 0);
      mx = fmaxf(fmaxf(mx, fmaxf(s[0], s[1])), fmaxf(s[2], s[3]));
    }
    mx = fmaxf(mx, __shfl_xor(mx, 16));
    mx = fmaxf(mx, __shfl_xor(mx, 32));

    // fold -mx into B1 q=3 hi word (hi/lo f16 split, exact to f32);
    // pairs against A1 q=3 slots j=2,3 which are 1.0.
    float mhf = (float)(_Float16)mx;
    fp16x2_t nm = __builtin_amdgcn_cvt_pkrtz(-mhf, -(mx - mhf));
    const unsigned w1B = (q4 == 3) ? __builtin_bit_cast(unsigned, nm) : w1A;
    U2H4 b1b; b1b.u = make_uint2(w0, w1B);

    // ---- Phase B: recompute s - mx, exp2, feed GEMM2 (lane-local, no LDS) ----
    float4_t d2 = zero4;
    #pragma unroll
    for (int p = 0; p < 8; ++p) {
      float4_t sa = __builtin_amdgcn_mfma_f32_16x16x16f16(a1[2 * p],     b1b.h, zero4, 0, 0, 0);
      float4_t sb = __builtin_amdgcn_mfma_f32_16x16x16f16(a1[2 * p + 1], b1b.h, zero4, 0, 0, 0);
      H4X2 b2;
      b2.e[0] = __builtin_amdgcn_cvt_pkrtz(__builtin_amdgcn_exp2f(sa[0]), __builtin_amdgcn_exp2f(sa[1]));
      b2.e[1] = __builtin_amdgcn_cvt_pkrtz(__builtin_amdgcn_exp2f(sa[2]), __builtin_amdgcn_exp2f(sa[3]));
      b2.e[2] = __builtin_amdgcn_cvt_pkrtz(__builtin_amdgcn_exp2f(sb[0]), __builtin_amdgcn_exp2f(sb[1]));
      b2.e[3] = __builtin_amdgcn_cvt_pkrtz(__builtin_amdgcn_exp2f(sb[2]), __builtin_amdgcn_exp2f(sb[3]));
      d2 = __builtin_amdgcn_mfma_f32_16x16x32_f16(a2[p], b2.h8, d2, 0, 0, 0);
    }

    // den at D2 row 4 = quad1 reg0; out comps at rows 0..3 = quad0 regs
    float den = __shfl(d2[0], zr + 16);
    if (lane < 16) {
      float r = __builtin_amdgcn_rcpf(den);
      float4 o = make_float4(d2[0] * r, d2[1] * r, d2[2] * r, d2[3] * r);
      out4[rowbase + zr] = o;
    }
  }
}

extern "C" void kernel_launch(void* const* d_in, const int* in_sizes, int n_in,
                              void* d_out, int out_size, void* d_ws, size_t ws_size,
                              hipStream_t stream) {
  const float4* x4    = (const float4*)d_in[0];  // (B, R) fp32 = NROWS float4
  const float*  c     = (const float*)d_in[1];   // (M, L) fp32
  const float*  sigma = (const float*)d_in[2];   // (1,)  fp32
  float4*       out4  = (float4*)d_out;          // (B, R) fp32

  _Float16* a1w = (_Float16*)d_ws;               // 16*64*4 f16 = 8 KiB
  _Float16* a2w = a1w + 16 * 64 * 4;             //  8*64*8 f16 = 8 KiB

  prep_kernel<<<6, 256, 0, stream>>>(c, sigma, a1w, a2w);
  sq_mfma_kernel<<<MAIN_BLOCKS, 256, 0, stream>>>(x4, a1w, a2w, out4);
}

// Round 10
// 103.263 us; speedup vs baseline: 1.3472x; 1.1107x over previous
//
#include <hip/hip_runtime.h>
#include <math.h>

// Problem constants
#define RDIM 512
#define MDIM 4
#define LDIM 256
#define BDIM 8192
#define NROWS (BDIM * (RDIM / MDIM))   // 1048576 rows of m=4
#define SIGMA_EPS 1e-4f
#define LOG2E 1.4426950408889634f
#define SHIFT_HEADROOM 96.0f           // exp2 recentre: args in (-inf, 96], cancels in q=e/den

typedef _Float16 half4_t __attribute__((ext_vector_type(4)));
typedef short    short8_t __attribute__((ext_vector_type(8)));
typedef __fp16   fp16x2_t __attribute__((ext_vector_type(2)));
typedef float    float4_t __attribute__((ext_vector_type(4)));

#define NRT (NROWS / 16)          // 65536 row-tiles of 16 z-rows
#define MAIN_BLOCKS 2048
#define WPB 4                      // waves per block
#define NT (NRT / (MAIN_BLOCKS * WPB))   // 8 row-tiles per wave

static __device__ __host__ inline unsigned short bf16_rne(float f) {
  unsigned u = __builtin_bit_cast(unsigned, f);
  return (unsigned short)((u + 0x7FFFu + ((u >> 16) & 1u)) >> 16);
}

// ---------------- prep: build MFMA A-operand fragments in ws ----------------
// GEMM1 (scores, 16x16x16 f16): A1[m=center][k], 16 tiles of 16 centers.
//   k by quad: q0,q1 -> uh0..3, q2 -> ul0..3, q3 -> [bh, bl, 1, 1]
//   (u = 2*sig*log2e*c hi/lo f16 split, b = -sig*log2e*||c||^2 split).
//   B1 z-slots: q0 -> zh, q1 -> zl, q2 -> zh, q3 -> [1,1, -U_h,-U_l]
//   with U = sig*log2e*||z||^2 - 96  (since 2z.c - c^2 <= z^2, s-U <= 96:
//   no overflow, and 96 extra exp2-units of underflow headroom so deep-tail
//   rows can't flush ALL q to zero -> den=0 -> NaN, which killed R9).
// GEMM2 (out^T = C2 @ Q, 16x16x32 bf16): 16 K-tiles in PERMUTED center order
//   center(p&7, k=8Q+j) = 32*(p&7) + 16*(j>>2) + 4Q + (j&3)
//   p<8: bf16_hi(c), m=4 row = 1.0 (den);  p>=8: bf16(c - hi) residual, m=4 = 0.
// B2 q-fragments are lane-local GEMM1 D registers (no LDS), bf16 (f32 exponent
// range; f16 would overflow at 2^96 / underflow below 2^-14).
__global__ void prep_kernel(const float* __restrict__ c, const float* __restrict__ sigma,
                            _Float16* __restrict__ a1w, unsigned short* __restrict__ a2w) {
  const int gid  = blockIdx.x * 256 + threadIdx.x;
  const int lane = gid & 63;
  const int q4   = lane >> 4;
  const int m    = lane & 15;
  const float sig   = fmaxf(sigma[0], 0.0f) + SIGMA_EPS;
  const float sigL  = sig * LOG2E;
  const float sig2L = 2.0f * sigL;
  if (gid < 1024) {
    const int t = gid >> 6;        // A1 tile
    const int l = t * 16 + m;      // center
    float cv[4];
    cv[0] = c[l]; cv[1] = c[256 + l]; cv[2] = c[512 + l]; cv[3] = c[768 + l];
    _Float16 uh[4], ul[4];
    #pragma unroll
    for (int i = 0; i < 4; ++i) {
      float u = sig2L * cv[i];
      uh[i] = (_Float16)u;
      ul[i] = (_Float16)(u - (float)uh[i]);
    }
    float bias = -sigL * fmaf(cv[0], cv[0], fmaf(cv[1], cv[1], fmaf(cv[2], cv[2], cv[3] * cv[3])));
    _Float16 bh = (_Float16)bias;
    _Float16 bl = (_Float16)(bias - (float)bh);
    #pragma unroll
    for (int j = 0; j < 4; ++j) {
      _Float16 v;
      if      (q4 <  2) v = uh[j];
      else if (q4 == 2) v = ul[j];
      else              v = (j == 0) ? bh : ((j == 1) ? bl : (_Float16)1.0f);  // k14/15 pair -U
      a1w[(t * 64 + lane) * 4 + j] = v;
    }
  } else if (gid < 2048) {
    const int p = (gid - 1024) >> 6;   // A2 K-tile, 0..15
    const int pc = p & 7;
    const bool hi = (p < 8);
    #pragma unroll
    for (int j = 0; j < 8; ++j) {
      int center = 32 * pc + 16 * (j >> 2) + 4 * q4 + (j & 3);   // permuted order
      unsigned short v = 0;
      if (m < 4) {
        float cf = c[m * 256 + center];
        unsigned short h = bf16_rne(cf);
        if (hi) v = h;
        else {
          float res = cf - __builtin_bit_cast(float, (unsigned)h << 16);
          v = bf16_rne(res);
        }
      } else if (m == 4) {
        v = hi ? (unsigned short)0x3F80 : (unsigned short)0;     // den ones-row (hi only)
      }
      a2w[(p * 64 + lane) * 8 + j] = v;
    }
  }
}

union U2H4 { uint2 u; half4_t h; };
union U4S8 { uint4 u; short8_t s; };

// ---------------- main ----------------
// Per wave, per 16-row tile (single pass, no max phase):
//  setup: z hi/lo f16 split; U = sigL*||z||^2 - 96 lane-local, folded into B1 q3.
//  loop p=0..7: 2x MFMA(16x16x16 f16) -> s - U; 8x exp2; 4x v_perm pack to bf16;
//               2x MFMA(16x16x32 bf16) vs c_hi / c_lo (+ den ones-row in hi).
//  D2: quad0 lanes hold out float4 (m=0..3); den at m=4 (quad1 reg0) -> one shfl.
__global__ __launch_bounds__(256, 4) void sq_mfma_kernel(
    const float4* __restrict__ x4,
    const _Float16* __restrict__ a1w,
    const unsigned short* __restrict__ a2w,
    const float* __restrict__ sigma,
    float4* __restrict__ out4) {
  const int tid  = threadIdx.x;
  const int lane = tid & 63;
  const int wave = tid >> 6;
  const int q4   = lane >> 4;
  const int zr   = lane & 15;

  const float sigL = (fmaxf(sigma[0], 0.0f) + SIGMA_EPS) * LOG2E;

  // preload loop-invariant A fragments (a1: 32 VGPR, a2: 64 VGPR)
  half4_t a1[16];
  short8_t a2[16];
  const half4_t* a1p = (const half4_t*)a1w;
  const short8_t* a2p = (const short8_t*)a2w;
  #pragma unroll
  for (int t = 0; t < 16; ++t) a1[t] = a1p[t * 64 + lane];
  #pragma unroll
  for (int p = 0; p < 16; ++p) a2[p] = a2p[p * 64 + lane];

  const int gw = blockIdx.x * WPB + wave;
  const float4_t zero4 = {0.f, 0.f, 0.f, 0.f};
  const unsigned one_one = 0x3C003C00u;   // f16 {1.0, 1.0}

  for (int it = 0; it < NT; ++it) {
    const int rowbase = (gw * NT + it) * 16;

    const float4 z = x4[rowbase + zr];
    // hi/lo f16 split of z (packed)
    fp16x2_t zh01 = __builtin_amdgcn_cvt_pkrtz(z.x, z.y);
    fp16x2_t zh23 = __builtin_amdgcn_cvt_pkrtz(z.z, z.w);
    fp16x2_t zl01 = __builtin_amdgcn_cvt_pkrtz(z.x - (float)zh01[0], z.y - (float)zh01[1]);
    fp16x2_t zl23 = __builtin_amdgcn_cvt_pkrtz(z.z - (float)zh23[0], z.w - (float)zh23[1]);
    const unsigned zh01u = __builtin_bit_cast(unsigned, zh01);
    const unsigned zh23u = __builtin_bit_cast(unsigned, zh23);
    const unsigned zl01u = __builtin_bit_cast(unsigned, zl01);
    const unsigned zl23u = __builtin_bit_cast(unsigned, zl23);

    // per-row shift: U = sigL*||z||^2 - 96 >= max score - 96 (lane-local).
    // s - U <= 96 (no f32 overflow: den <= 2^104), and survival window extends
    // to sigL*dist^2 < 222 -> no all-zero rows -> no den==0 NaN.
    float U = sigL * fmaf(z.x, z.x, fmaf(z.y, z.y, fmaf(z.z, z.z, z.w * z.w))) - SHIFT_HEADROOM;
    float Uh = (float)(_Float16)U;
    fp16x2_t nU = __builtin_amdgcn_cvt_pkrtz(-Uh, -(U - Uh));

    // B1 by quad: q0 -> zh (pairs uh), q1 -> zl (pairs uh), q2 -> zh (pairs ul),
    // q3 -> [1,1 | -U_h,-U_l] (1,1 pair bh,bl; -U pairs A's 1,1)
    const unsigned w0 = (q4 == 1) ? zl01u : ((q4 == 3) ? one_one : zh01u);
    const unsigned w1 = (q4 == 3) ? __builtin_bit_cast(unsigned, nU)
                                  : ((q4 == 1) ? zl23u : zh23u);
    U2H4 b1; b1.u = make_uint2(w0, w1);

    // single pass: scores -> exp2 -> bf16 -> GEMM2 (all lane-local)
    float4_t d2 = zero4;
    #pragma unroll
    for (int p = 0; p < 8; ++p) {
      float4_t sa = __builtin_amdgcn_mfma_f32_16x16x16f16(a1[2 * p],     b1.h, zero4, 0, 0, 0);
      float4_t sb = __builtin_amdgcn_mfma_f32_16x16x16f16(a1[2 * p + 1], b1.h, zero4, 0, 0, 0);
      float e0 = __builtin_amdgcn_exp2f(sa[0]);
      float e1 = __builtin_amdgcn_exp2f(sa[1]);
      float e2 = __builtin_amdgcn_exp2f(sa[2]);
      float e3 = __builtin_amdgcn_exp2f(sa[3]);
      float e4 = __builtin_amdgcn_exp2f(sb[0]);
      float e5 = __builtin_amdgcn_exp2f(sb[1]);
      float e6 = __builtin_amdgcn_exp2f(sb[2]);
      float e7 = __builtin_amdgcn_exp2f(sb[3]);
      // pack pairs to bf16 (truncate: keep high 16 bits) via v_perm
      U4S8 b2;
      b2.u.x = __builtin_amdgcn_perm(__builtin_bit_cast(unsigned, e1),
                                     __builtin_bit_cast(unsigned, e0), 0x07060302u);
      b2.u.y = __builtin_amdgcn_perm(__builtin_bit_cast(unsigned, e3),
                                     __builtin_bit_cast(unsigned, e2), 0x07060302u);
      b2.u.z = __builtin_amdgcn_perm(__builtin_bit_cast(unsigned, e5),
                                     __builtin_bit_cast(unsigned, e4), 0x07060302u);
      b2.u.w = __builtin_amdgcn_perm(__builtin_bit_cast(unsigned, e7),
                                     __builtin_bit_cast(unsigned, e6), 0x07060302u);
      d2 = __builtin_amdgcn_mfma_f32_16x16x32_bf16(a2[p],     b2.s, d2, 0, 0, 0);  // c_hi + den
      d2 = __builtin_amdgcn_mfma_f32_16x16x32_bf16(a2[p + 8], b2.s, d2, 0, 0, 0);  // c_lo
    }

    // den at D2 row 4 = quad1 reg0; out comps at rows 0..3 = quad0 regs
    float den = __shfl(d2[0], zr + 16);
    if (lane < 16) {
      float r = __builtin_amdgcn_rcpf(den);
      float4 o = make_float4(d2[0] * r, d2[1] * r, d2[2] * r, d2[3] * r);
      out4[rowbase + zr] = o;
    }
  }
}

extern "C" void kernel_launch(void* const* d_in, const int* in_sizes, int n_in,
                              void* d_out, int out_size, void* d_ws, size_t ws_size,
                              hipStream_t stream) {
  const float4* x4    = (const float4*)d_in[0];  // (B, R) fp32 = NROWS float4
  const float*  c     = (const float*)d_in[1];   // (M, L) fp32
  const float*  sigma = (const float*)d_in[2];   // (1,)  fp32
  float4*       out4  = (float4*)d_out;          // (B, R) fp32

  _Float16*       a1w = (_Float16*)d_ws;                 // 16*64*4 f16 = 8 KiB
  unsigned short* a2w = (unsigned short*)(a1w + 16 * 64 * 4);  // 16*64*8 bf16 = 16 KiB

  prep_kernel<<<8, 256, 0, stream>>>(c, sigma, a1w, a2w);
  sq_mfma_kernel<<<MAIN_BLOCKS, 256, 0, stream>>>(x4, a1w, a2w, sigma, out4);
}

// Round 11
// 98.900 us; speedup vs baseline: 1.4067x; 1.0441x over previous
//
#include <hip/hip_runtime.h>
#include <math.h>

// Problem constants
#define RDIM 512
#define MDIM 4
#define LDIM 256
#define BDIM 8192
#define NROWS (BDIM * (RDIM / MDIM))   // 1048576 rows of m=4
#define SIGMA_EPS 1e-4f
#define LOG2E 1.4426950408889634f
#define SHIFT_HEADROOM 96.0f           // exp2 recentre: args in (-inf, 96], cancels in q=e/den

typedef _Float16 half4_t __attribute__((ext_vector_type(4)));
typedef short    short8_t __attribute__((ext_vector_type(8)));
typedef __fp16   fp16x2_t __attribute__((ext_vector_type(2)));
typedef float    float4_t __attribute__((ext_vector_type(4)));

#define NRT (NROWS / 16)          // 65536 row-tiles of 16 z-rows
#define MAIN_BLOCKS 2048
#define WPB 4                      // waves per block
#define NT (NRT / (MAIN_BLOCKS * WPB))   // 8 row-tiles per wave (walked in pairs)

static __device__ __host__ inline unsigned short bf16_rne(float f) {
  unsigned u = __builtin_bit_cast(unsigned, f);
  return (unsigned short)((u + 0x7FFFu + ((u >> 16) & 1u)) >> 16);
}

// ---------------- prep: build MFMA A-operand fragments in ws ----------------
// GEMM1 (scores, 16x16x16 f16): A1[m=center][k], 16 tiles of 16 centers.
//   k by quad: q0,q1 -> uh0..3, q2 -> ul0..3, q3 -> [bh, bl, 1, 1]
//   (u = 2*sig*log2e*c hi/lo f16 split, b = -sig*log2e*||c||^2 split).
//   B1 z-slots: q0 -> zh, q1 -> zl, q2 -> zh, q3 -> [1,1, -U_h,-U_l]
//   U = sig*log2e*||z||^2 - 96 (upper bound shift, no max pass; 96 headroom
//   prevents den==0 underflow NaN — R9 lesson).
// GEMM2 (out^T = C2 @ Q, 16x16x32 bf16): 8 K-tiles, PERMUTED center order
//   center(p, k=8Q+j) = 32p + 16*(j>>2) + 4Q + (j&3)
//   rows m=0..3: bf16_rne(c)  (c_lo residual dropped: error ~2^-9|c|, noise
//   vs 0.0719 threshold); m=4: 1.0 (den row).
// B2 q-fragments are lane-local GEMM1 D registers (no LDS), bf16 (range).
__global__ void prep_kernel(const float* __restrict__ c, const float* __restrict__ sigma,
                            _Float16* __restrict__ a1w, unsigned short* __restrict__ a2w) {
  const int gid  = blockIdx.x * 256 + threadIdx.x;
  const int lane = gid & 63;
  const int q4   = lane >> 4;
  const int m    = lane & 15;
  const float sig   = fmaxf(sigma[0], 0.0f) + SIGMA_EPS;
  const float sigL  = sig * LOG2E;
  const float sig2L = 2.0f * sigL;
  if (gid < 1024) {
    const int t = gid >> 6;        // A1 tile
    const int l = t * 16 + m;      // center
    float cv[4];
    cv[0] = c[l]; cv[1] = c[256 + l]; cv[2] = c[512 + l]; cv[3] = c[768 + l];
    _Float16 uh[4], ul[4];
    #pragma unroll
    for (int i = 0; i < 4; ++i) {
      float u = sig2L * cv[i];
      uh[i] = (_Float16)u;
      ul[i] = (_Float16)(u - (float)uh[i]);
    }
    float bias = -sigL * fmaf(cv[0], cv[0], fmaf(cv[1], cv[1], fmaf(cv[2], cv[2], cv[3] * cv[3])));
    _Float16 bh = (_Float16)bias;
    _Float16 bl = (_Float16)(bias - (float)bh);
    #pragma unroll
    for (int j = 0; j < 4; ++j) {
      _Float16 v;
      if      (q4 <  2) v = uh[j];
      else if (q4 == 2) v = ul[j];
      else              v = (j == 0) ? bh : ((j == 1) ? bl : (_Float16)1.0f);  // k14/15 pair -U
      a1w[(t * 64 + lane) * 4 + j] = v;
    }
  } else if (gid < 1536) {
    const int p = (gid - 1024) >> 6;   // A2 K-tile, 0..7
    #pragma unroll
    for (int j = 0; j < 8; ++j) {
      int center = 32 * p + 16 * (j >> 2) + 4 * q4 + (j & 3);   // permuted order
      unsigned short v = 0;
      if (m < 4)       v = bf16_rne(c[m * 256 + center]);
      else if (m == 4) v = (unsigned short)0x3F80;              // den ones-row
      a2w[(p * 64 + lane) * 8 + j] = v;
    }
  }
}

union U2H4 { uint2 u; half4_t h; };
union U4S8 { uint4 u; short8_t s; };

struct B1Frag { U2H4 b1; };

static __device__ __forceinline__ U2H4 make_b1(const float4& z, float sigL, int q4,
                                               unsigned one_one) {
  fp16x2_t zh01 = __builtin_amdgcn_cvt_pkrtz(z.x, z.y);
  fp16x2_t zh23 = __builtin_amdgcn_cvt_pkrtz(z.z, z.w);
  fp16x2_t zl01 = __builtin_amdgcn_cvt_pkrtz(z.x - (float)zh01[0], z.y - (float)zh01[1]);
  fp16x2_t zl23 = __builtin_amdgcn_cvt_pkrtz(z.z - (float)zh23[0], z.w - (float)zh23[1]);
  const unsigned zh01u = __builtin_bit_cast(unsigned, zh01);
  const unsigned zh23u = __builtin_bit_cast(unsigned, zh23);
  const unsigned zl01u = __builtin_bit_cast(unsigned, zl01);
  const unsigned zl23u = __builtin_bit_cast(unsigned, zl23);
  float U = sigL * fmaf(z.x, z.x, fmaf(z.y, z.y, fmaf(z.z, z.z, z.w * z.w))) - SHIFT_HEADROOM;
  float Uh = (float)(_Float16)U;
  fp16x2_t nU = __builtin_amdgcn_cvt_pkrtz(-Uh, -(U - Uh));
  const unsigned w0 = (q4 == 1) ? zl01u : ((q4 == 3) ? one_one : zh01u);
  const unsigned w1 = (q4 == 3) ? __builtin_bit_cast(unsigned, nU)
                                : ((q4 == 1) ? zl23u : zh23u);
  U2H4 b1; b1.u = make_uint2(w0, w1);
  return b1;
}

// ---------------- main ----------------
// Two row-tiles interleaved per loop body (independent chains -> ILP to hide
// MFMA/exp2 latency at low occupancy), dual d2 accumulators (chain 8 -> 4),
// z prefetch one pair ahead. Single pass, no max phase (U-shift in B1 q3).
__global__ __launch_bounds__(256, 3) void sq_mfma_kernel(
    const float4* __restrict__ x4,
    const _Float16* __restrict__ a1w,
    const unsigned short* __restrict__ a2w,
    const float* __restrict__ sigma,
    float4* __restrict__ out4) {
  const int tid  = threadIdx.x;
  const int lane = tid & 63;
  const int wave = tid >> 6;
  const int q4   = lane >> 4;
  const int zr   = lane & 15;

  const float sigL = (fmaxf(sigma[0], 0.0f) + SIGMA_EPS) * LOG2E;

  // preload loop-invariant A fragments (a1: 32 VGPR, a2: 32 VGPR)
  half4_t a1[16];
  short8_t a2[8];
  const half4_t* a1p = (const half4_t*)a1w;
  const short8_t* a2p = (const short8_t*)a2w;
  #pragma unroll
  for (int t = 0; t < 16; ++t) a1[t] = a1p[t * 64 + lane];
  #pragma unroll
  for (int p = 0; p < 8; ++p) a2[p] = a2p[p * 64 + lane];

  const int gw = blockIdx.x * WPB + wave;
  const int tilebase = gw * NT;
  const float4_t zero4 = {0.f, 0.f, 0.f, 0.f};
  const unsigned one_one = 0x3C003C00u;   // f16 {1.0, 1.0}

  // prime the z pipeline (pair 0)
  float4 zA = x4[(tilebase + 0) * 16 + zr];
  float4 zB = x4[(tilebase + 1) * 16 + zr];

  for (int it = 0; it < NT; it += 2) {
    // prefetch next pair (clamped; uniform condition-free)
    const int itn = (it + 2 < NT) ? (it + 2) : it;
    float4 zAn = x4[(tilebase + itn) * 16 + zr];
    float4 zBn = x4[(tilebase + itn + 1) * 16 + zr];

    U2H4 b1A = make_b1(zA, sigL, q4, one_one);
    U2H4 b1B = make_b1(zB, sigL, q4, one_one);

    float4_t d2A0 = zero4, d2A1 = zero4, d2B0 = zero4, d2B1 = zero4;
    #pragma unroll
    for (int p = 0; p < 8; ++p) {
      float4_t saA = __builtin_amdgcn_mfma_f32_16x16x16f16(a1[2 * p],     b1A.h, zero4, 0, 0, 0);
      float4_t sbA = __builtin_amdgcn_mfma_f32_16x16x16f16(a1[2 * p + 1], b1A.h, zero4, 0, 0, 0);
      float4_t saB = __builtin_amdgcn_mfma_f32_16x16x16f16(a1[2 * p],     b1B.h, zero4, 0, 0, 0);
      float4_t sbB = __builtin_amdgcn_mfma_f32_16x16x16f16(a1[2 * p + 1], b1B.h, zero4, 0, 0, 0);

      U4S8 b2A, b2B;
      {
        float e0 = __builtin_amdgcn_exp2f(saA[0]);
        float e1 = __builtin_amdgcn_exp2f(saA[1]);
        float e2 = __builtin_amdgcn_exp2f(saA[2]);
        float e3 = __builtin_amdgcn_exp2f(saA[3]);
        float e4 = __builtin_amdgcn_exp2f(sbA[0]);
        float e5 = __builtin_amdgcn_exp2f(sbA[1]);
        float e6 = __builtin_amdgcn_exp2f(sbA[2]);
        float e7 = __builtin_amdgcn_exp2f(sbA[3]);
        b2A.u.x = __builtin_amdgcn_perm(__builtin_bit_cast(unsigned, e1),
                                        __builtin_bit_cast(unsigned, e0), 0x07060302u);
        b2A.u.y = __builtin_amdgcn_perm(__builtin_bit_cast(unsigned, e3),
                                        __builtin_bit_cast(unsigned, e2), 0x07060302u);
        b2A.u.z = __builtin_amdgcn_perm(__builtin_bit_cast(unsigned, e5),
                                        __builtin_bit_cast(unsigned, e4), 0x07060302u);
        b2A.u.w = __builtin_amdgcn_perm(__builtin_bit_cast(unsigned, e7),
                                        __builtin_bit_cast(unsigned, e6), 0x07060302u);
      }
      {
        float e0 = __builtin_amdgcn_exp2f(saB[0]);
        float e1 = __builtin_amdgcn_exp2f(saB[1]);
        float e2 = __builtin_amdgcn_exp2f(saB[2]);
        float e3 = __builtin_amdgcn_exp2f(saB[3]);
        float e4 = __builtin_amdgcn_exp2f(sbB[0]);
        float e5 = __builtin_amdgcn_exp2f(sbB[1]);
        float e6 = __builtin_amdgcn_exp2f(sbB[2]);
        float e7 = __builtin_amdgcn_exp2f(sbB[3]);
        b2B.u.x = __builtin_amdgcn_perm(__builtin_bit_cast(unsigned, e1),
                                        __builtin_bit_cast(unsigned, e0), 0x07060302u);
        b2B.u.y = __builtin_amdgcn_perm(__builtin_bit_cast(unsigned, e3),
                                        __builtin_bit_cast(unsigned, e2), 0x07060302u);
        b2B.u.z = __builtin_amdgcn_perm(__builtin_bit_cast(unsigned, e5),
                                        __builtin_bit_cast(unsigned, e4), 0x07060302u);
        b2B.u.w = __builtin_amdgcn_perm(__builtin_bit_cast(unsigned, e7),
                                        __builtin_bit_cast(unsigned, e6), 0x07060302u);
      }
      if (p & 1) {
        d2A1 = __builtin_amdgcn_mfma_f32_16x16x32_bf16(a2[p], b2A.s, d2A1, 0, 0, 0);
        d2B1 = __builtin_amdgcn_mfma_f32_16x16x32_bf16(a2[p], b2B.s, d2B1, 0, 0, 0);
      } else {
        d2A0 = __builtin_amdgcn_mfma_f32_16x16x32_bf16(a2[p], b2A.s, d2A0, 0, 0, 0);
        d2B0 = __builtin_amdgcn_mfma_f32_16x16x32_bf16(a2[p], b2B.s, d2B0, 0, 0, 0);
      }
    }

    float4_t d2A = d2A0 + d2A1;
    float4_t d2B = d2B0 + d2B1;

    // den at D2 row 4 = quad1 reg0; out comps at rows 0..3 = quad0 regs
    float denA = __shfl(d2A[0], zr + 16);
    float denB = __shfl(d2B[0], zr + 16);
    if (lane < 16) {
      float rA = __builtin_amdgcn_rcpf(denA);
      float rB = __builtin_amdgcn_rcpf(denB);
      out4[(tilebase + it) * 16 + zr] =
          make_float4(d2A[0] * rA, d2A[1] * rA, d2A[2] * rA, d2A[3] * rA);
      out4[(tilebase + it + 1) * 16 + zr] =
          make_float4(d2B[0] * rB, d2B[1] * rB, d2B[2] * rB, d2B[3] * rB);
    }

    zA = zAn; zB = zBn;
  }
}

extern "C" void kernel_launch(void* const* d_in, const int* in_sizes, int n_in,
                              void* d_out, int out_size, void* d_ws, size_t ws_size,
                              hipStream_t stream) {
  const float4* x4    = (const float4*)d_in[0];  // (B, R) fp32 = NROWS float4
  const float*  c     = (const float*)d_in[1];   // (M, L) fp32
  const float*  sigma = (const float*)d_in[2];   // (1,)  fp32
  float4*       out4  = (float4*)d_out;          // (B, R) fp32

  _Float16*       a1w = (_Float16*)d_ws;                 // 16*64*4 f16 = 8 KiB
  unsigned short* a2w = (unsigned short*)(a1w + 16 * 64 * 4);  // 8*64*8 bf16 = 8 KiB

  prep_kernel<<<6, 256, 0, stream>>>(c, sigma, a1w, a2w);
  sq_mfma_kernel<<<MAIN_BLOCKS, 256, 0, stream>>>(x4, a1w, a2w, sigma, out4);
}

// Round 12
// 97.994 us; speedup vs baseline: 1.4197x; 1.0092x over previous
//
#include <hip/hip_runtime.h>
#include <math.h>

// Problem constants
#define RDIM 512
#define MDIM 4
#define LDIM 256
#define BDIM 8192
#define NROWS (BDIM * (RDIM / MDIM))   // 1048576 rows of m=4
#define SIGMA_EPS 1e-4f
#define LOG2E 1.4426950408889634f
#define SHIFT_HEADROOM 96.0f           // exp2 recentre: args in (-inf, 96], cancels in q=e/den

typedef _Float16 half4_t __attribute__((ext_vector_type(4)));
typedef short    short8_t __attribute__((ext_vector_type(8)));
typedef __fp16   fp16x2_t __attribute__((ext_vector_type(2)));
typedef float    float4_t __attribute__((ext_vector_type(4)));

#define NRT (NROWS / 16)          // 65536 row-tiles of 16 z-rows
#define MAIN_BLOCKS 2048
#define WPB 4                      // waves per block
#define NT (NRT / (MAIN_BLOCKS * WPB))   // 8 row-tiles per wave (walked in quads)
#define QUAD 4                     // interleaved independent tile-chains per wave

static __device__ __host__ inline unsigned short bf16_rne(float f) {
  unsigned u = __builtin_bit_cast(unsigned, f);
  return (unsigned short)((u + 0x7FFFu + ((u >> 16) & 1u)) >> 16);
}

// ---------------- prep: build MFMA A-operand fragments in ws ----------------
// GEMM1 (scores, 16x16x16 f16): A1[m=center][k], 16 tiles of 16 centers.
//   k by quad: q0,q1 -> uh0..3, q2 -> ul0..3, q3 -> [bh, bl, 1, 1]
//   (u = 2*sig*log2e*c hi/lo f16 split, b = -sig*log2e*||c||^2 split).
//   B1 z-slots: q0 -> zh, q1 -> zl, q2 -> zh, q3 -> [1,1, -U_h,-U_l]
//   U = sig*log2e*||z||^2 - 96 (upper-bound shift, no max pass; 96 headroom
//   prevents den==0 underflow NaN — R9 lesson).
// GEMM2 (out^T = C2 @ Q, 16x16x32 bf16): 8 K-tiles, PERMUTED center order
//   center(p, k=8Q+j) = 32p + 16*(j>>2) + 4Q + (j&3)
//   rows m=0..3: bf16_rne(c); m=4: 1.0 (den row).
// B2 q-fragments are lane-local GEMM1 D registers (no LDS), bf16 (range).
__global__ void prep_kernel(const float* __restrict__ c, const float* __restrict__ sigma,
                            _Float16* __restrict__ a1w, unsigned short* __restrict__ a2w) {
  const int gid  = blockIdx.x * 256 + threadIdx.x;
  const int lane = gid & 63;
  const int q4   = lane >> 4;
  const int m    = lane & 15;
  const float sig   = fmaxf(sigma[0], 0.0f) + SIGMA_EPS;
  const float sigL  = sig * LOG2E;
  const float sig2L = 2.0f * sigL;
  if (gid < 1024) {
    const int t = gid >> 6;        // A1 tile
    const int l = t * 16 + m;      // center
    float cv[4];
    cv[0] = c[l]; cv[1] = c[256 + l]; cv[2] = c[512 + l]; cv[3] = c[768 + l];
    _Float16 uh[4], ul[4];
    #pragma unroll
    for (int i = 0; i < 4; ++i) {
      float u = sig2L * cv[i];
      uh[i] = (_Float16)u;
      ul[i] = (_Float16)(u - (float)uh[i]);
    }
    float bias = -sigL * fmaf(cv[0], cv[0], fmaf(cv[1], cv[1], fmaf(cv[2], cv[2], cv[3] * cv[3])));
    _Float16 bh = (_Float16)bias;
    _Float16 bl = (_Float16)(bias - (float)bh);
    #pragma unroll
    for (int j = 0; j < 4; ++j) {
      _Float16 v;
      if      (q4 <  2) v = uh[j];
      else if (q4 == 2) v = ul[j];
      else              v = (j == 0) ? bh : ((j == 1) ? bl : (_Float16)1.0f);  // k14/15 pair -U
      a1w[(t * 64 + lane) * 4 + j] = v;
    }
  } else if (gid < 1536) {
    const int p = (gid - 1024) >> 6;   // A2 K-tile, 0..7
    #pragma unroll
    for (int j = 0; j < 8; ++j) {
      int center = 32 * p + 16 * (j >> 2) + 4 * q4 + (j & 3);   // permuted order
      unsigned short v = 0;
      if (m < 4)       v = bf16_rne(c[m * 256 + center]);
      else if (m == 4) v = (unsigned short)0x3F80;              // den ones-row
      a2w[(p * 64 + lane) * 8 + j] = v;
    }
  }
}

union U2H4 { uint2 u; half4_t h; };
union U4S8 { uint4 u; short8_t s; };

static __device__ __forceinline__ U2H4 make_b1(const float4& z, float sigL, int q4,
                                               unsigned one_one) {
  fp16x2_t zh01 = __builtin_amdgcn_cvt_pkrtz(z.x, z.y);
  fp16x2_t zh23 = __builtin_amdgcn_cvt_pkrtz(z.z, z.w);
  fp16x2_t zl01 = __builtin_amdgcn_cvt_pkrtz(z.x - (float)zh01[0], z.y - (float)zh01[1]);
  fp16x2_t zl23 = __builtin_amdgcn_cvt_pkrtz(z.z - (float)zh23[0], z.w - (float)zh23[1]);
  const unsigned zh01u = __builtin_bit_cast(unsigned, zh01);
  const unsigned zh23u = __builtin_bit_cast(unsigned, zh23);
  const unsigned zl01u = __builtin_bit_cast(unsigned, zl01);
  const unsigned zl23u = __builtin_bit_cast(unsigned, zl23);
  float U = sigL * fmaf(z.x, z.x, fmaf(z.y, z.y, fmaf(z.z, z.z, z.w * z.w))) - SHIFT_HEADROOM;
  float Uh = (float)(_Float16)U;
  fp16x2_t nU = __builtin_amdgcn_cvt_pkrtz(-Uh, -(U - Uh));
  const unsigned w0 = (q4 == 1) ? zl01u : ((q4 == 3) ? one_one : zh01u);
  const unsigned w1 = (q4 == 3) ? __builtin_bit_cast(unsigned, nU)
                                : ((q4 == 1) ? zl23u : zh23u);
  U2H4 b1; b1.u = make_uint2(w0, w1);
  return b1;
}

// ---------------- main ----------------
// QUAD=4 independent row-tile chains interleaved per loop body: per p,
// 8x GEMM1 MFMA + 32 exp2 + 16 v_perm + 4x GEMM2 MFMA across 4 chains ->
// each chain's serial d2 dependency is hidden under the other 3 chains' work.
// Single pass, no max phase (upper-bound U-shift folded into B1 q3).
__global__ __launch_bounds__(256, 3) void sq_mfma_kernel(
    const float4* __restrict__ x4,
    const _Float16* __restrict__ a1w,
    const unsigned short* __restrict__ a2w,
    const float* __restrict__ sigma,
    float4* __restrict__ out4) {
  const int tid  = threadIdx.x;
  const int lane = tid & 63;
  const int wave = tid >> 6;
  const int q4   = lane >> 4;
  const int zr   = lane & 15;

  const float sigL = (fmaxf(sigma[0], 0.0f) + SIGMA_EPS) * LOG2E;

  // preload loop-invariant A fragments (a1: 32 VGPR, a2: 32 VGPR)
  half4_t a1[16];
  short8_t a2[8];
  const half4_t* a1p = (const half4_t*)a1w;
  const short8_t* a2p = (const short8_t*)a2w;
  #pragma unroll
  for (int t = 0; t < 16; ++t) a1[t] = a1p[t * 64 + lane];
  #pragma unroll
  for (int p = 0; p < 8; ++p) a2[p] = a2p[p * 64 + lane];

  const int gw = blockIdx.x * WPB + wave;
  const int tilebase = gw * NT;
  const float4_t zero4 = {0.f, 0.f, 0.f, 0.f};
  const unsigned one_one = 0x3C003C00u;   // f16 {1.0, 1.0}

  // prime the z pipeline (quad 0)
  float4 zq[QUAD];
  #pragma unroll
  for (int ch = 0; ch < QUAD; ++ch) zq[ch] = x4[(tilebase + ch) * 16 + zr];

  for (int it = 0; it < NT; it += QUAD) {
    // prefetch next quad (clamped)
    const int itn = (it + QUAD < NT) ? (it + QUAD) : it;
    float4 zn[QUAD];
    #pragma unroll
    for (int ch = 0; ch < QUAD; ++ch) zn[ch] = x4[(tilebase + itn + ch) * 16 + zr];

    U2H4 b1[QUAD];
    #pragma unroll
    for (int ch = 0; ch < QUAD; ++ch) b1[ch] = make_b1(zq[ch], sigL, q4, one_one);

    float4_t d2[QUAD];
    #pragma unroll
    for (int ch = 0; ch < QUAD; ++ch) d2[ch] = zero4;

    #pragma unroll
    for (int p = 0; p < 8; ++p) {
      float4_t sa[QUAD], sb[QUAD];
      #pragma unroll
      for (int ch = 0; ch < QUAD; ++ch) {
        sa[ch] = __builtin_amdgcn_mfma_f32_16x16x16f16(a1[2 * p],     b1[ch].h, zero4, 0, 0, 0);
        sb[ch] = __builtin_amdgcn_mfma_f32_16x16x16f16(a1[2 * p + 1], b1[ch].h, zero4, 0, 0, 0);
      }
      #pragma unroll
      for (int ch = 0; ch < QUAD; ++ch) {
        float e0 = __builtin_amdgcn_exp2f(sa[ch][0]);
        float e1 = __builtin_amdgcn_exp2f(sa[ch][1]);
        float e2 = __builtin_amdgcn_exp2f(sa[ch][2]);
        float e3 = __builtin_amdgcn_exp2f(sa[ch][3]);
        float e4 = __builtin_amdgcn_exp2f(sb[ch][0]);
        float e5 = __builtin_amdgcn_exp2f(sb[ch][1]);
        float e6 = __builtin_amdgcn_exp2f(sb[ch][2]);
        float e7 = __builtin_amdgcn_exp2f(sb[ch][3]);
        U4S8 b2;
        b2.u.x = __builtin_amdgcn_perm(__builtin_bit_cast(unsigned, e1),
                                       __builtin_bit_cast(unsigned, e0), 0x07060302u);
        b2.u.y = __builtin_amdgcn_perm(__builtin_bit_cast(unsigned, e3),
                                       __builtin_bit_cast(unsigned, e2), 0x07060302u);
        b2.u.z = __builtin_amdgcn_perm(__builtin_bit_cast(unsigned, e5),
                                       __builtin_bit_cast(unsigned, e4), 0x07060302u);
        b2.u.w = __builtin_amdgcn_perm(__builtin_bit_cast(unsigned, e7),
                                       __builtin_bit_cast(unsigned, e6), 0x07060302u);
        d2[ch] = __builtin_amdgcn_mfma_f32_16x16x32_bf16(a2[p], b2.s, d2[ch], 0, 0, 0);
      }
    }

    // den at D2 row 4 = quad1 reg0; out comps at rows 0..3 = quad0 regs
    float den[QUAD];
    #pragma unroll
    for (int ch = 0; ch < QUAD; ++ch) den[ch] = __shfl(d2[ch][0], zr + 16);
    if (lane < 16) {
      #pragma unroll
      for (int ch = 0; ch < QUAD; ++ch) {
        float r = __builtin_amdgcn_rcpf(den[ch]);
        out4[(tilebase + it + ch) * 16 + zr] =
            make_float4(d2[ch][0] * r, d2[ch][1] * r, d2[ch][2] * r, d2[ch][3] * r);
      }
    }

    #pragma unroll
    for (int ch = 0; ch < QUAD; ++ch) zq[ch] = zn[ch];
  }
}

extern "C" void kernel_launch(void* const* d_in, const int* in_sizes, int n_in,
                              void* d_out, int out_size, void* d_ws, size_t ws_size,
                              hipStream_t stream) {
  const float4* x4    = (const float4*)d_in[0];  // (B, R) fp32 = NROWS float4
  const float*  c     = (const float*)d_in[1];   // (M, L) fp32
  const float*  sigma = (const float*)d_in[2];   // (1,)  fp32
  float4*       out4  = (float4*)d_out;          // (B, R) fp32

  _Float16*       a1w = (_Float16*)d_ws;                 // 16*64*4 f16 = 8 KiB
  unsigned short* a2w = (unsigned short*)(a1w + 16 * 64 * 4);  // 8*64*8 bf16 = 8 KiB

  prep_kernel<<<6, 256, 0, stream>>>(c, sigma, a1w, a2w);
  sq_mfma_kernel<<<MAIN_BLOCKS, 256, 0, stream>>>(x4, a1w, a2w, sigma, out4);
}